// Round 1
// baseline (373.322 us; speedup 1.0000x reference)
//
#include <hip/hip_runtime.h>

typedef unsigned short u16;
typedef short s16x8 __attribute__((ext_vector_type(8)));
typedef float f32x4 __attribute__((ext_vector_type(4)));

#define AS1 __attribute__((address_space(1)))
#define AS3 __attribute__((address_space(3)))

// B=2, SQ=SKV=2048, H=1024, NH=16, HD=64
// rows (B*S) = 4096, K = N = 1024 for all projection GEMMs.

__device__ __forceinline__ u16 f2bf(float f) {
  unsigned u = __float_as_uint(f);
  u += 0x7fffu + ((u >> 16) & 1u);      // RNE
  return (u16)(u >> 16);
}
__device__ __forceinline__ float bf2f(u16 b) {
  return __uint_as_float(((unsigned)b) << 16);
}
__device__ __forceinline__ void gld16(const void* g, void* l) {
  // async global->LDS, 16B per lane; LDS dest is wave-uniform base + lane*16
  __builtin_amdgcn_global_load_lds((const AS1 unsigned int*)g,
                                   (AS3 unsigned int*)l, 16, 0, 0);
}

// ---------------- prep: fp32 -> bf16 (+ additive mask) ----------------
// virtual vec4 index space over all segments (sizes are compile-time):
// q:[0,1048576) kv:[.. ,2097152) Wq:2359296 Wk:2621440 Wv:2883584 Wo:3145728 mask:5242880
__global__ __launch_bounds__(256) void prep_kernel(
    const float* __restrict__ qs, const float* __restrict__ kvs, const float* __restrict__ mk,
    const float* __restrict__ wq, const float* __restrict__ wk, const float* __restrict__ wv,
    const float* __restrict__ wo,
    u16* __restrict__ q_bf, u16* __restrict__ kv_bf, u16* __restrict__ am_bf,
    u16* __restrict__ wq_bf, u16* __restrict__ wk_bf, u16* __restrict__ wv_bf,
    u16* __restrict__ wo_bf)
{
  const int stride = gridDim.x * blockDim.x;
  for (int v = blockIdx.x * blockDim.x + threadIdx.x; v < 5242880; v += stride) {
    const float* s; u16* d; int off; bool ismask = false;
    if (v < 1048576)      { s = qs;  d = q_bf;  off = v; }
    else if (v < 2097152) { s = kvs; d = kv_bf; off = v - 1048576; }
    else if (v < 2359296) { s = wq;  d = wq_bf; off = v - 2097152; }
    else if (v < 2621440) { s = wk;  d = wk_bf; off = v - 2359296; }
    else if (v < 2883584) { s = wv;  d = wv_bf; off = v - 2621440; }
    else if (v < 3145728) { s = wo;  d = wo_bf; off = v - 2883584; }
    else                  { s = mk;  d = am_bf; off = v - 3145728; ismask = true; }
    float4 f = ((const float4*)s)[off];
    if (ismask) {
      f.x = (1.f - f.x) * -10000.f; f.y = (1.f - f.y) * -10000.f;
      f.z = (1.f - f.z) * -10000.f; f.w = (1.f - f.w) * -10000.f;
    }
    ushort4 o;
    o.x = f2bf(f.x); o.y = f2bf(f.y); o.z = f2bf(f.z); o.w = f2bf(f.w);
    ((ushort4*)d)[off] = o;
  }
}

// ---------------- 128x128 bf16 NT GEMM (C = A * W^T), m97 structure ----------------
// LDS tiles are k-octet("slot")-major: [4 slots][128 rows][8 bf16] so that
//  (a) global_load_lds dest is linear (wave w stages slot w), and
//  (b) fragment ds_read_b128 of 16 rows x 16B is 256B-contiguous -> conflict-free.
template<int EPI>  // 0: bf16 out in [B*NH][S][64] head-split layout; 1: fp32 out [row][1024]
__device__ __forceinline__ void gemm_body(
    const u16* __restrict__ A, const u16* __restrict__ W, const float* __restrict__ bias,
    void* __restrict__ outp, float alpha)
{
  constexpr int K = 1024;
  __shared__ u16 As[4096], Bs[4096];
  const int tid = threadIdx.x, wave = tid >> 6, lane = tid & 63;
  const int l15 = lane & 15, l4 = lane >> 4;
  const int bid = blockIdx.x;
  const int swz = (bid & 7) * 32 + (bid >> 3);   // XCD-contiguous M-bands (256 blocks, bijective)
  const int m0 = (swz >> 3) * 128, n0 = (swz & 7) * 128;
  const int wr = wave >> 1, wc = wave & 1;

  const u16* ag0 = A + (size_t)(m0 + lane) * K + wave * 8;
  const u16* ag1 = A + (size_t)(m0 + 64 + lane) * K + wave * 8;
  const u16* bg0 = W + (size_t)(n0 + lane) * K + wave * 8;
  const u16* bg1 = W + (size_t)(n0 + 64 + lane) * K + wave * 8;
  u16* al0 = As + wave * 1024; u16* al1 = al0 + 512;
  u16* bl0 = Bs + wave * 1024; u16* bl1 = bl0 + 512;
  const int aoff = l4 * 1024 + (wr * 64 + l15) * 8;   // elem idx: slot*1024 + row*8
  const int boff = l4 * 1024 + (wc * 64 + l15) * 8;

  f32x4 acc[4][4] = {};

  for (int kt = 0; kt < 32; ++kt) {
    const int ko = kt * 32;
    gld16(ag0 + ko, al0);
    gld16(ag1 + ko, al1);
    gld16(bg0 + ko, bl0);
    gld16(bg1 + ko, bl1);
    asm volatile("s_waitcnt vmcnt(0)");
    __syncthreads();
    s16x8 af[4], bf[4];
    #pragma unroll
    for (int m = 0; m < 4; ++m) af[m] = *(const s16x8*)(As + aoff + m * 128);
    #pragma unroll
    for (int n = 0; n < 4; ++n) bf[n] = *(const s16x8*)(Bs + boff + n * 128);
    #pragma unroll
    for (int m = 0; m < 4; ++m)
      #pragma unroll
      for (int n = 0; n < 4; ++n)
        acc[m][n] = __builtin_amdgcn_mfma_f32_16x16x32_bf16(af[m], bf[n], acc[m][n], 0, 0, 0);
    __syncthreads();
  }

  #pragma unroll
  for (int n = 0; n < 4; ++n) {
    const int col = n0 + wc * 64 + n * 16 + l15;
    const float bv = bias ? bias[col] : 0.f;
    #pragma unroll
    for (int m = 0; m < 4; ++m) {
      #pragma unroll
      for (int r = 0; r < 4; ++r) {
        const int row = m0 + wr * 64 + m * 16 + l4 * 4 + r;  // D: col=lane&15, row=(lane>>4)*4+r
        const float val = (acc[m][n][r] + bv) * alpha;
        if constexpr (EPI == 0) {
          const int bb = row >> 11, ss = row & 2047, hh = col >> 6, dd = col & 63;
          ((u16*)outp)[(((size_t)(bb * 16 + hh)) * 2048 + ss) * 64 + dd] = f2bf(val);
        } else {
          ((float*)outp)[(size_t)row * 1024 + col] = val;
        }
      }
    }
  }
}

__global__ __launch_bounds__(256) void gemm_qkv(
    const u16* __restrict__ qbf, const u16* __restrict__ kvbf,
    const u16* __restrict__ wqb, const u16* __restrict__ wkb, const u16* __restrict__ wvb,
    const float* __restrict__ bq, const float* __restrict__ bv,
    u16* __restrict__ Qh, u16* __restrict__ Kh, u16* __restrict__ Vh)
{
  const int which = blockIdx.y;               // 0:Q 1:K 2:V
  const u16* A = (which == 0) ? qbf : kvbf;
  const u16* W = (which == 0) ? wqb : (which == 1 ? wkb : wvb);
  const float* bias = (which == 0) ? bq : (which == 1 ? (const float*)nullptr : bv);
  u16* out = (which == 0) ? Qh : (which == 1 ? Kh : Vh);
  const float alpha = (which == 0) ? 0.125f : 1.0f;   // fold 1/sqrt(64) into Q
  gemm_body<0>(A, W, bias, out, alpha);
}

__global__ __launch_bounds__(256) void gemm_out(
    const u16* __restrict__ ctx, const u16* __restrict__ wob,
    const float* __restrict__ bo, float* __restrict__ out)
{
  gemm_body<1>(ctx, wob, bo, out, 1.0f);
}

// ---------------- flash attention ----------------
// grid (SQ/64, B*NH); 4 waves; wave w owns q-rows [q0+16w, q0+16w+16).
// Ks: [8 kslots][64 kv][8]  (QK^T B-frags conflict-free, staged via global_load_lds)
// Vt: V^T slot-major [8 kvslots][64 d][8] (PV B-frags conflict-free; reg-staged transpose)
// Pl: per-wave P round-trip [8 kvslots][16 q][8]
__global__ __launch_bounds__(256) void attn_kernel(
    const u16* __restrict__ Qh, const u16* __restrict__ Kh,
    const u16* __restrict__ Vh, const u16* __restrict__ am,
    u16* __restrict__ ctx)
{
  __shared__ u16 Ks[4096];
  __shared__ u16 Vt[4096];
  __shared__ u16 Pl[4][1024];
  const int tid = threadIdx.x, wave = tid >> 6, lane = tid & 63;
  const int l15 = lane & 15, l4 = lane >> 4;
  const int hh = blockIdx.y, b = hh >> 4, h = hh & 15;
  const int q0 = blockIdx.x * 64;
  const u16* Qb = Qh + (size_t)hh * 2048 * 64;
  const u16* Kb = Kh + (size_t)hh * 2048 * 64;
  const u16* Vb = Vh + (size_t)hh * 2048 * 64;

  // Q fragments held in registers for the whole kernel (scale already folded in)
  const s16x8 qf0 = *(const s16x8*)(Qb + (size_t)(q0 + wave * 16 + l15) * 64 + l4 * 8);
  const s16x8 qf1 = *(const s16x8*)(Qb + (size_t)(q0 + wave * 16 + l15) * 64 + 32 + l4 * 8);

  f32x4 of[4] = {};
  float mrow[4] = {-1e30f, -1e30f, -1e30f, -1e30f};
  float lrow[4] = {0.f, 0.f, 0.f, 0.f};
  const u16* amb = am + ((size_t)b * 2048 + q0 + wave * 16) * 2048;

  for (int kt = 0; kt < 32; ++kt) {
    const int kv0 = kt * 64;
    __syncthreads();                      // prev tile fully consumed
    // K tile: wave stages kslots 2w, 2w+1 (linear LDS dest)
    gld16(Kb + (size_t)(kv0 + lane) * 64 + (wave * 2) * 8,     Ks + wave * 1024);
    gld16(Kb + (size_t)(kv0 + lane) * 64 + (wave * 2 + 1) * 8, Ks + wave * 1024 + 512);
    // V tile: reg-staged transpose into kv-slot-major V^T
    {
      int idx = tid;
      #pragma unroll
      for (int it = 0; it < 2; ++it, idx += 256) {
        const int kvr = idx >> 3, d0 = (idx & 7) * 8;
        const s16x8 v = *(const s16x8*)(Vb + (size_t)(kv0 + kvr) * 64 + d0);
        u16* wp = Vt + (kvr >> 3) * 512 + (kvr & 7);
        #pragma unroll
        for (int j = 0; j < 8; ++j) wp[(d0 + j) * 8] = (u16)v[j];
      }
    }
    asm volatile("s_waitcnt vmcnt(0)");
    __syncthreads();                      // tiles ready

    // S = Q K^T  (q on D-rows, kv on D-cols)
    f32x4 sf[4];
    #pragma unroll
    for (int nf = 0; nf < 4; ++nf) {
      const s16x8 k0 = *(const s16x8*)(Ks + (0 + l4) * 512 + (nf * 16 + l15) * 8);
      const s16x8 k1 = *(const s16x8*)(Ks + (4 + l4) * 512 + (nf * 16 + l15) * 8);
      f32x4 s = {0.f, 0.f, 0.f, 0.f};
      s = __builtin_amdgcn_mfma_f32_16x16x32_bf16(qf0, k0, s, 0, 0, 0);
      s = __builtin_amdgcn_mfma_f32_16x16x32_bf16(qf1, k1, s, 0, 0, 0);
      sf[nf] = s;
    }
    // additive mask + online softmax
    float tmax[4] = {-1e30f, -1e30f, -1e30f, -1e30f};
    #pragma unroll
    for (int nf = 0; nf < 4; ++nf)
      #pragma unroll
      for (int r = 0; r < 4; ++r) {
        const float a = bf2f(amb[(size_t)(l4 * 4 + r) * 2048 + kv0 + nf * 16 + l15]);
        const float sv = sf[nf][r] + a;
        sf[nf][r] = sv;
        tmax[r] = fmaxf(tmax[r], sv);
      }
    #pragma unroll
    for (int r = 0; r < 4; ++r) {
      tmax[r] = fmaxf(tmax[r], __shfl_xor(tmax[r], 1));
      tmax[r] = fmaxf(tmax[r], __shfl_xor(tmax[r], 2));
      tmax[r] = fmaxf(tmax[r], __shfl_xor(tmax[r], 4));
      tmax[r] = fmaxf(tmax[r], __shfl_xor(tmax[r], 8));
    }
    float psum[4];
    #pragma unroll
    for (int r = 0; r < 4; ++r) {
      const float mn = fmaxf(mrow[r], tmax[r]);
      const float sc = __expf(mrow[r] - mn);
      mrow[r] = mn;
      lrow[r] *= sc;
      psum[r] = 0.f;
      #pragma unroll
      for (int nf = 0; nf < 4; ++nf) {
        const float p = __expf(sf[nf][r] - mn);
        psum[r] += p;
        // P[q=l4*4+r][kv=nf*16+l15] -> Pl slot-major: slot=kv>>3, j=kv&7
        Pl[wave][(nf * 2 + (l15 >> 3)) * 128 + (l4 * 4 + r) * 8 + (lane & 7)] = f2bf(p);
      }
      #pragma unroll
      for (int nd = 0; nd < 4; ++nd) of[nd][r] *= sc;
    }
    #pragma unroll
    for (int r = 0; r < 4; ++r) {
      psum[r] += __shfl_xor(psum[r], 1);
      psum[r] += __shfl_xor(psum[r], 2);
      psum[r] += __shfl_xor(psum[r], 4);
      psum[r] += __shfl_xor(psum[r], 8);
      lrow[r] += psum[r];
    }
    __syncthreads();                      // P writes visible (also orders Vt reads)

    // O += P V   (A-frag: q=lane&15, kv=(lane>>4)*8+j  -> from Pl)
    const s16x8 pa0 = *(const s16x8*)(Pl[wave] + (0 + l4) * 128 + l15 * 8);
    const s16x8 pa1 = *(const s16x8*)(Pl[wave] + (4 + l4) * 128 + l15 * 8);
    #pragma unroll
    for (int nd = 0; nd < 4; ++nd) {
      const s16x8 v0 = *(const s16x8*)(Vt + (0 + l4) * 512 + (nd * 16 + l15) * 8);
      const s16x8 v1 = *(const s16x8*)(Vt + (4 + l4) * 512 + (nd * 16 + l15) * 8);
      of[nd] = __builtin_amdgcn_mfma_f32_16x16x32_bf16(pa0, v0, of[nd], 0, 0, 0);
      of[nd] = __builtin_amdgcn_mfma_f32_16x16x32_bf16(pa1, v1, of[nd], 0, 0, 0);
    }
  }

  // epilogue: normalize, write ctx in [B,S,H] (bf16) for the O-projection GEMM
  #pragma unroll
  for (int r = 0; r < 4; ++r) {
    const float inv = 1.f / lrow[r];
    const int qg = q0 + wave * 16 + l4 * 4 + r;
    const size_t rowbase = ((size_t)b * 2048 + qg) * 1024 + h * 64;
    #pragma unroll
    for (int nd = 0; nd < 4; ++nd)
      ctx[rowbase + nd * 16 + l15] = f2bf(of[nd][r] * inv);
  }
}

// ---------------- launcher ----------------
extern "C" void kernel_launch(void* const* d_in, const int* in_sizes, int n_in,
                              void* d_out, int out_size, void* d_ws, size_t ws_size,
                              hipStream_t stream)
{
  const float* qs = (const float*)d_in[0];
  const float* kvs = (const float*)d_in[1];
  const float* mk = (const float*)d_in[2];
  const float* Wq = (const float*)d_in[3];
  const float* bq = (const float*)d_in[4];
  const float* Wk = (const float*)d_in[5];
  const float* Wv = (const float*)d_in[6];
  const float* bv = (const float*)d_in[7];
  const float* Wo = (const float*)d_in[8];
  const float* bo = (const float*)d_in[9];
  float* out = (float*)d_out;

  char* ws = (char*)d_ws;
  u16* q_bf  = (u16*)(ws + 0);          // 8,388,608 B
  u16* kv_bf = (u16*)(ws + 8388608);    // 8,388,608
  u16* wq_bf = (u16*)(ws + 16777216);   // 2,097,152
  u16* wk_bf = (u16*)(ws + 18874368);   // 2,097,152
  u16* wv_bf = (u16*)(ws + 20971520);   // 2,097,152
  u16* wo_bf = (u16*)(ws + 23068672);   // 2,097,152
  u16* am_bf = (u16*)(ws + 25165824);   // 16,777,216
  u16* Qhp   = (u16*)(ws + 41943040);   // 8,388,608  [B*NH][S][64]
  u16* Khp   = (u16*)(ws + 50331648);   // 8,388,608
  u16* Vhp   = (u16*)(ws + 58720256);   // 8,388,608
  u16* ctxp  = (u16*)(ws + 67108864);   // 8,388,608  -> total 75,497,472 B

  prep_kernel<<<dim3(2048), dim3(256), 0, stream>>>(
      qs, kvs, mk, Wq, Wk, Wv, Wo, q_bf, kv_bf, am_bf, wq_bf, wk_bf, wv_bf, wo_bf);

  gemm_qkv<<<dim3(256, 3), dim3(256), 0, stream>>>(
      q_bf, kv_bf, wq_bf, wk_bf, wv_bf, bq, bv, Qhp, Khp, Vhp);

  attn_kernel<<<dim3(32, 32), dim3(256), 0, stream>>>(Qhp, Khp, Vhp, am_bf, ctxp);

  gemm_out<<<dim3(256), dim3(256), 0, stream>>>(ctxp, wo_bf, bo, out);
}

// Round 2
// 360.763 us; speedup vs baseline: 1.0348x; 1.0348x over previous
//
#include <hip/hip_runtime.h>

typedef unsigned short u16;
typedef unsigned int u32;
typedef short s16x8 __attribute__((ext_vector_type(8)));
typedef float f32x4 __attribute__((ext_vector_type(4)));

#define AS1 __attribute__((address_space(1)))
#define AS3 __attribute__((address_space(3)))

// B=2, SQ=SKV=2048, H=1024, NH=16, HD=64

__device__ __forceinline__ u16 f2bf(float f) {
  unsigned u = __float_as_uint(f);
  u += 0x7fffu + ((u >> 16) & 1u);      // RNE
  return (u16)(u >> 16);
}
__device__ __forceinline__ float bf2f(u16 b) {
  return __uint_as_float(((unsigned)b) << 16);
}
__device__ __forceinline__ u32 pack2(float a, float b) {
  return (u32)f2bf(a) | ((u32)f2bf(b) << 16);
}
__device__ __forceinline__ void gld16(const void* g, void* l) {
  __builtin_amdgcn_global_load_lds((const AS1 unsigned int*)g,
                                   (AS3 unsigned int*)l, 16, 0, 0);
}

// ---------------- prep: fp32 -> bf16 (+ additive mask) ----------------
__global__ __launch_bounds__(256) void prep_kernel(
    const float* __restrict__ qs, const float* __restrict__ kvs, const float* __restrict__ mk,
    const float* __restrict__ wq, const float* __restrict__ wk, const float* __restrict__ wv,
    const float* __restrict__ wo,
    u16* __restrict__ q_bf, u16* __restrict__ kv_bf, u16* __restrict__ am_bf,
    u16* __restrict__ wq_bf, u16* __restrict__ wk_bf, u16* __restrict__ wv_bf,
    u16* __restrict__ wo_bf)
{
  const int stride = gridDim.x * blockDim.x;
  for (int v = blockIdx.x * blockDim.x + threadIdx.x; v < 5242880; v += stride) {
    const float* s; u16* d; int off; bool ismask = false;
    if (v < 1048576)      { s = qs;  d = q_bf;  off = v; }
    else if (v < 2097152) { s = kvs; d = kv_bf; off = v - 1048576; }
    else if (v < 2359296) { s = wq;  d = wq_bf; off = v - 2097152; }
    else if (v < 2621440) { s = wk;  d = wk_bf; off = v - 2359296; }
    else if (v < 2883584) { s = wv;  d = wv_bf; off = v - 2621440; }
    else if (v < 3145728) { s = wo;  d = wo_bf; off = v - 2883584; }
    else                  { s = mk;  d = am_bf; off = v - 3145728; ismask = true; }
    float4 f = ((const float4*)s)[off];
    if (ismask) {
      f.x = (1.f - f.x) * -10000.f; f.y = (1.f - f.y) * -10000.f;
      f.z = (1.f - f.z) * -10000.f; f.w = (1.f - f.w) * -10000.f;
    }
    ushort4 o;
    o.x = f2bf(f.x); o.y = f2bf(f.y); o.z = f2bf(f.z); o.w = f2bf(f.w);
    ((ushort4*)d)[off] = o;
  }
}

// ---------------- 128x128 bf16 NT GEMM (C = A * W^T), 2-phase dbuf ----------------
// LDS tiles k-slot-major: [4 slots][128 rows][8 bf16] -> linear gld16 dest AND
// 256B-contiguous conflict-free ds_read_b128 fragments.
// EPI 0: bf16 out, head-split [B*NH][2048][64], bias per col, *alpha
// EPI 1: fp32 out [4096][1024], bias per col
// EPI 2: bf16 out = V^T: C rows are d_global, cols are (b,s); out [B*NH][64][2048], bias per ROW
template<int EPI>
__device__ __forceinline__ void gemm_body(
    const u16* __restrict__ A, const u16* __restrict__ W, const float* __restrict__ bias,
    void* __restrict__ outp, float alpha, int m0, int n0)
{
  __shared__ u16 As[2][4096], Bs[2][4096];
  const int tid = threadIdx.x, wave = tid >> 6, lane = tid & 63;
  const int l15 = lane & 15, l4 = lane >> 4;
  const int wr = wave >> 1, wc = wave & 1;

  const u16* ag0 = A + (size_t)(m0 + lane) * 1024 + wave * 8;
  const u16* ag1 = A + (size_t)(m0 + 64 + lane) * 1024 + wave * 8;
  const u16* bg0 = W + (size_t)(n0 + lane) * 1024 + wave * 8;
  const u16* bg1 = W + (size_t)(n0 + 64 + lane) * 1024 + wave * 8;
  const int aoff = l4 * 1024 + (wr * 64 + l15) * 8;   // element offsets
  const int boff = l4 * 1024 + (wc * 64 + l15) * 8;

  f32x4 acc[4][4] = {};

  // prologue: stage kt=0 into buf 0
  gld16(ag0, &As[0][wave * 1024]);
  gld16(ag1, &As[0][wave * 1024 + 512]);
  gld16(bg0, &Bs[0][wave * 1024]);
  gld16(bg1, &Bs[0][wave * 1024 + 512]);
  asm volatile("s_waitcnt vmcnt(0)");
  __syncthreads();

  int cur = 0;
  for (int kt = 0; kt < 32; ++kt) {
    if (kt < 31) {                       // issue next-tile loads BEFORE compute
      const int ko = (kt + 1) * 32;
      gld16(ag0 + ko, &As[cur ^ 1][wave * 1024]);
      gld16(ag1 + ko, &As[cur ^ 1][wave * 1024 + 512]);
      gld16(bg0 + ko, &Bs[cur ^ 1][wave * 1024]);
      gld16(bg1 + ko, &Bs[cur ^ 1][wave * 1024 + 512]);
    }
    s16x8 af[4], bf[4];
    #pragma unroll
    for (int m = 0; m < 4; ++m) af[m] = *(const s16x8*)(&As[cur][0] + aoff + m * 128);
    #pragma unroll
    for (int n = 0; n < 4; ++n) bf[n] = *(const s16x8*)(&Bs[cur][0] + boff + n * 128);
    #pragma unroll
    for (int m = 0; m < 4; ++m)
      #pragma unroll
      for (int n = 0; n < 4; ++n)
        acc[m][n] = __builtin_amdgcn_mfma_f32_16x16x32_bf16(af[m], bf[n], acc[m][n], 0, 0, 0);
    asm volatile("s_waitcnt vmcnt(0)");
    __syncthreads();
    cur ^= 1;
  }

  #pragma unroll
  for (int n = 0; n < 4; ++n) {
    const int col = n0 + wc * 64 + n * 16 + l15;
    #pragma unroll
    for (int m = 0; m < 4; ++m) {
      #pragma unroll
      for (int r = 0; r < 4; ++r) {
        const int row = m0 + wr * 64 + m * 16 + l4 * 4 + r;
        if constexpr (EPI == 0) {
          const float val = (acc[m][n][r] + (bias ? bias[col] : 0.f)) * alpha;
          const int bb = row >> 11, ss = row & 2047, hh = col >> 6, dd = col & 63;
          ((u16*)outp)[(((size_t)(bb * 16 + hh)) * 2048 + ss) * 64 + dd] = f2bf(val);
        } else if constexpr (EPI == 1) {
          ((float*)outp)[(size_t)row * 1024 + col] = acc[m][n][r] + (bias ? bias[col] : 0.f);
        } else {  // EPI==2: V^T
          const float val = acc[m][n][r] + bias[row];
          const int hh = row >> 6, dd = row & 63, bb = col >> 11, ss = col & 2047;
          ((u16*)outp)[(((size_t)(bb * 16 + hh)) * 64 + dd) * 2048 + ss] = f2bf(val);
        }
      }
    }
  }
}

__global__ __launch_bounds__(256) void gemm_qkv(
    const u16* __restrict__ qbf, const u16* __restrict__ kvbf,
    const u16* __restrict__ wqb, const u16* __restrict__ wkb, const u16* __restrict__ wvb,
    const float* __restrict__ bq, const float* __restrict__ bv,
    u16* __restrict__ Qh, u16* __restrict__ Kh, u16* __restrict__ Vt)
{
  const int bid = blockIdx.x;
  const int swz = (bid & 7) * 32 + (bid >> 3);   // XCD-contiguous chunks (256 = 8*32, bijective)
  const int which = blockIdx.y;
  if (which == 0)
    gemm_body<0>(qbf, wqb, bq, Qh, 0.125f, (swz >> 3) * 128, (swz & 7) * 128);
  else if (which == 1)
    gemm_body<0>(kvbf, wkb, nullptr, Kh, 1.0f, (swz >> 3) * 128, (swz & 7) * 128);
  else   // V^T = Wv * KV^T  (M=1024 d-rows, N=4096 s-cols)
    gemm_body<2>(wvb, kvbf, bv, Vt, 1.0f, (swz >> 5) * 128, (swz & 31) * 128);
}

__global__ __launch_bounds__(256) void gemm_out(
    const u16* __restrict__ ctx, const u16* __restrict__ wob,
    const float* __restrict__ bo, float* __restrict__ out)
{
  const int bid = blockIdx.x;
  const int swz = (bid & 7) * 32 + (bid >> 3);
  gemm_body<1>(ctx, wob, bo, out, 1.0f, (swz >> 3) * 128, (swz & 7) * 128);
}

// ---------------- flash attention (swapped QK^T, dbuf, 1 barrier/tile) ----------------
// grid: 1024 blocks 1D, XCD-chunked -> 4 heads per XCD (K/V 2MB fits L2).
// Per block: 64 q rows, 4 waves x 16 q. S^T = K*Q^T so kv is lane-local:
//   vector mask loads, scalar m/l, u32-packed P writes.
// Ks[2][8 dslot][64 kv][8], Vs[2][8 kvslot][64 d][8] (from pre-transposed V^T),
// Pl[4][8 kvslot][16 q][8] -- all fragment ds_read_b128 256B-contiguous.
__global__ __launch_bounds__(256) void attn_kernel(
    const u16* __restrict__ Qh, const u16* __restrict__ Kh,
    const u16* __restrict__ Vt, const u16* __restrict__ am,
    u16* __restrict__ ctx)
{
  __shared__ u16 Ks[2][8][64][8];
  __shared__ u16 Vs[2][8][64][8];
  __shared__ u16 Pl[4][8][16][8];
  const int tid = threadIdx.x, wave = tid >> 6, lane = tid & 63;
  const int l15 = lane & 15, l4 = lane >> 4;
  const int bid = blockIdx.x;
  const int pos = (bid & 7) * 128 + (bid >> 3);   // XCD-chunked
  const int hh = pos >> 5, qt = pos & 31;
  const int b = hh >> 4, h = hh & 15;
  const int q0 = qt * 64;
  const u16* Qb = Qh + (size_t)hh * 2048 * 64;
  const u16* Kb = Kh + (size_t)hh * 2048 * 64;
  const u16* Vb = Vt + (size_t)hh * 64 * 2048;

  // Q B-frag (col=q=l15, k=d=l4*8+j); scale folded in at projection
  const int qrow = q0 + wave * 16 + l15;
  const s16x8 qf0 = *(const s16x8*)(Qb + (size_t)qrow * 64 + l4 * 8);
  const s16x8 qf1 = *(const s16x8*)(Qb + (size_t)qrow * 64 + 32 + l4 * 8);

  f32x4 of[4] = {};
  float m_run = -1e30f, l_run = 0.f;
  const u16* amrow = am + ((size_t)b * 2048 + qrow) * 2048;

  auto stage = [&](int buf, int kt) {
    const int kv0 = kt * 64;
    gld16(Kb + (size_t)(kv0 + lane) * 64 + (wave * 2) * 8,     &Ks[buf][wave * 2][0][0]);
    gld16(Kb + (size_t)(kv0 + lane) * 64 + (wave * 2 + 1) * 8, &Ks[buf][wave * 2 + 1][0][0]);
    gld16(Vb + (size_t)lane * 2048 + kv0 + (wave * 2) * 8,     &Vs[buf][wave * 2][0][0]);
    gld16(Vb + (size_t)lane * 2048 + kv0 + (wave * 2 + 1) * 8, &Vs[buf][wave * 2 + 1][0][0]);
  };

  stage(0, 0);
  asm volatile("s_waitcnt vmcnt(0)");
  __syncthreads();

  int cur = 0;
  for (int kt = 0; kt < 32; ++kt) {
    if (kt < 31) stage(cur ^ 1, kt + 1);
    const int kv0 = kt * 64;

    // mask: 4 vector loads (kv contiguous per lane in S^T space)
    ushort4 mk4[4];
    #pragma unroll
    for (int nf = 0; nf < 4; ++nf)
      mk4[nf] = *(const ushort4*)(amrow + kv0 + nf * 16 + l4 * 4);

    // S^T = K * Q^T : lane holds q=l15, kv_local = nf*16 + l4*4 + r
    f32x4 sf[4];
    #pragma unroll
    for (int nf = 0; nf < 4; ++nf) {
      const s16x8 ka0 = *(const s16x8*)(&Ks[cur][l4][nf * 16 + l15][0]);
      const s16x8 ka1 = *(const s16x8*)(&Ks[cur][4 + l4][nf * 16 + l15][0]);
      f32x4 s = {0.f, 0.f, 0.f, 0.f};
      s = __builtin_amdgcn_mfma_f32_16x16x32_bf16(ka0, qf0, s, 0, 0, 0);
      s = __builtin_amdgcn_mfma_f32_16x16x32_bf16(ka1, qf1, s, 0, 0, 0);
      sf[nf] = s;
    }

    // mask add + tile max (per-lane, then across the 4 l4-groups)
    float tmax = -1e30f;
    #pragma unroll
    for (int nf = 0; nf < 4; ++nf)
      #pragma unroll
      for (int r = 0; r < 4; ++r) {
        const float sv = sf[nf][r] + bf2f(((const u16*)&mk4[nf])[r]);
        sf[nf][r] = sv;
        tmax = fmaxf(tmax, sv);
      }
    tmax = fmaxf(tmax, __shfl_xor(tmax, 16));
    tmax = fmaxf(tmax, __shfl_xor(tmax, 32));

    const float mn = fmaxf(m_run, tmax);
    const float sc = __expf(m_run - mn);
    m_run = mn;
    float psum = 0.f;
    #pragma unroll
    for (int nf = 0; nf < 4; ++nf) {
      const float p0 = __expf(sf[nf][0] - mn), p1 = __expf(sf[nf][1] - mn);
      const float p2 = __expf(sf[nf][2] - mn), p3 = __expf(sf[nf][3] - mn);
      psum += (p0 + p1) + (p2 + p3);
      u32* w = (u32*)&Pl[wave][nf * 2 + (l4 >> 1)][l15][(l4 & 1) * 4];
      w[0] = pack2(p0, p1);
      w[1] = pack2(p2, p3);
    }
    psum += __shfl_xor(psum, 16);
    psum += __shfl_xor(psum, 32);
    l_run = l_run * sc + psum;

    // O rescale (O lane rows are q = l4*4+r; sc lives at lane q)
    float sq[4];
    #pragma unroll
    for (int r = 0; r < 4; ++r) sq[r] = __shfl(sc, l4 * 4 + r);
    #pragma unroll
    for (int nd = 0; nd < 4; ++nd)
      #pragma unroll
      for (int r = 0; r < 4; ++r) of[nd][r] *= sq[r];

    // O += P * V
    #pragma unroll
    for (int kh = 0; kh < 2; ++kh) {
      const s16x8 pa = *(const s16x8*)(&Pl[wave][kh * 4 + l4][l15][0]);
      #pragma unroll
      for (int nd = 0; nd < 4; ++nd) {
        const s16x8 vb = *(const s16x8*)(&Vs[cur][kh * 4 + l4][nd * 16 + l15][0]);
        of[nd] = __builtin_amdgcn_mfma_f32_16x16x32_bf16(pa, vb, of[nd], 0, 0, 0);
      }
    }
    asm volatile("s_waitcnt vmcnt(0)");
    __syncthreads();
    cur ^= 1;
  }

  // epilogue: normalize + write ctx [B][S][H] bf16
  const float inv = 1.f / l_run;
  float invq[4];
  #pragma unroll
  for (int r = 0; r < 4; ++r) invq[r] = __shfl(inv, l4 * 4 + r);
  #pragma unroll
  for (int r = 0; r < 4; ++r) {
    const int qg = q0 + wave * 16 + l4 * 4 + r;
    const size_t rowbase = ((size_t)b * 2048 + qg) * 1024 + h * 64;
    #pragma unroll
    for (int nd = 0; nd < 4; ++nd)
      ctx[rowbase + nd * 16 + l15] = f2bf(of[nd][r] * invq[r]);
  }
}

// ---------------- launcher ----------------
extern "C" void kernel_launch(void* const* d_in, const int* in_sizes, int n_in,
                              void* d_out, int out_size, void* d_ws, size_t ws_size,
                              hipStream_t stream)
{
  const float* qs = (const float*)d_in[0];
  const float* kvs = (const float*)d_in[1];
  const float* mk = (const float*)d_in[2];
  const float* Wq = (const float*)d_in[3];
  const float* bq = (const float*)d_in[4];
  const float* Wk = (const float*)d_in[5];
  const float* Wv = (const float*)d_in[6];
  const float* bv = (const float*)d_in[7];
  const float* Wo = (const float*)d_in[8];
  const float* bo = (const float*)d_in[9];
  float* out = (float*)d_out;

  char* ws = (char*)d_ws;
  u16* q_bf  = (u16*)(ws + 0);
  u16* kv_bf = (u16*)(ws + 8388608);
  u16* wq_bf = (u16*)(ws + 16777216);
  u16* wk_bf = (u16*)(ws + 18874368);
  u16* wv_bf = (u16*)(ws + 20971520);
  u16* wo_bf = (u16*)(ws + 23068672);
  u16* am_bf = (u16*)(ws + 25165824);
  u16* Qhp   = (u16*)(ws + 41943040);   // [B*NH][2048][64]
  u16* Khp   = (u16*)(ws + 50331648);   // [B*NH][2048][64]
  u16* Vtp   = (u16*)(ws + 58720256);   // [B*NH][64][2048]  (pre-transposed)
  u16* ctxp  = (u16*)(ws + 67108864);   // [B][2048][1024]

  prep_kernel<<<dim3(2048), dim3(256), 0, stream>>>(
      qs, kvs, mk, Wq, Wk, Wv, Wo, q_bf, kv_bf, am_bf, wq_bf, wk_bf, wv_bf, wo_bf);

  gemm_qkv<<<dim3(256, 3), dim3(256), 0, stream>>>(
      q_bf, kv_bf, wq_bf, wk_bf, wv_bf, bq, bv, Qhp, Khp, Vtp);

  attn_kernel<<<dim3(1024), dim3(256), 0, stream>>>(Qhp, Khp, Vtp, am_bf, ctxp);

  gemm_out<<<dim3(256), dim3(256), 0, stream>>>(ctxp, wo_bf, bo, out);
}

// Round 3
// 315.290 us; speedup vs baseline: 1.1841x; 1.1442x over previous
//
#include <hip/hip_runtime.h>

typedef unsigned short u16;
typedef unsigned int u32;
typedef short s16x8 __attribute__((ext_vector_type(8)));
typedef float f32x4 __attribute__((ext_vector_type(4)));

#define AS1 __attribute__((address_space(1)))
#define AS3 __attribute__((address_space(3)))

// B=2, SQ=SKV=2048, H=1024, NH=16, HD=64

__device__ __forceinline__ u16 f2bf(float f) {
  unsigned u = __float_as_uint(f);
  u += 0x7fffu + ((u >> 16) & 1u);      // RNE
  return (u16)(u >> 16);
}
__device__ __forceinline__ float bf2f(u16 b) {
  return __uint_as_float(((unsigned)b) << 16);
}
__device__ __forceinline__ u32 pack2(float a, float b) {
  return (u32)f2bf(a) | ((u32)f2bf(b) << 16);
}
__device__ __forceinline__ void gld16(const void* g, void* l) {
  __builtin_amdgcn_global_load_lds((const AS1 unsigned int*)g,
                                   (AS3 unsigned int*)l, 16, 0, 0);
}

// ---------------- prep: fp32 -> bf16 (+ additive mask) ----------------
__global__ __launch_bounds__(256) void prep_kernel(
    const float* __restrict__ qs, const float* __restrict__ kvs, const float* __restrict__ mk,
    const float* __restrict__ wq, const float* __restrict__ wk, const float* __restrict__ wv,
    const float* __restrict__ wo,
    u16* __restrict__ q_bf, u16* __restrict__ kv_bf, u16* __restrict__ am_bf,
    u16* __restrict__ wq_bf, u16* __restrict__ wk_bf, u16* __restrict__ wv_bf,
    u16* __restrict__ wo_bf)
{
  const int stride = gridDim.x * blockDim.x;
  for (int v = blockIdx.x * blockDim.x + threadIdx.x; v < 5242880; v += stride) {
    const float* s; u16* d; int off; bool ismask = false;
    if (v < 1048576)      { s = qs;  d = q_bf;  off = v; }
    else if (v < 2097152) { s = kvs; d = kv_bf; off = v - 1048576; }
    else if (v < 2359296) { s = wq;  d = wq_bf; off = v - 2097152; }
    else if (v < 2621440) { s = wk;  d = wk_bf; off = v - 2359296; }
    else if (v < 2883584) { s = wv;  d = wv_bf; off = v - 2621440; }
    else if (v < 3145728) { s = wo;  d = wo_bf; off = v - 2883584; }
    else                  { s = mk;  d = am_bf; off = v - 3145728; ismask = true; }
    float4 f = ((const float4*)s)[off];
    if (ismask) {
      f.x = (1.f - f.x) * -10000.f; f.y = (1.f - f.y) * -10000.f;
      f.z = (1.f - f.z) * -10000.f; f.w = (1.f - f.w) * -10000.f;
    }
    ushort4 o;
    o.x = f2bf(f.x); o.y = f2bf(f.y); o.z = f2bf(f.z); o.w = f2bf(f.w);
    ((ushort4*)d)[off] = o;
  }
}

// ---------------- 128x128 bf16 NT GEMM, ring-3 counted-vmcnt pipeline ----------------
// LDS per buffer: A[128][32] u16 row-major (64B rows). Staging gld16 covers 16
// rows x 64B (coalesced 64B segments). Frag reads XOR-swizzled: phys_slot =
// l4 ^ ((row>>1)&3); store side pre-swizzles the GLOBAL source (rule #21).
template<int EPI>
__device__ __forceinline__ void gemm_body(
    const u16* __restrict__ A, const u16* __restrict__ W, const float* __restrict__ bias,
    void* __restrict__ outp, float alpha, int m0, int n0)
{
  __shared__ u16 As[3][4096], Bs[3][4096];
  const int tid = threadIdx.x, wave = tid >> 6, lane = tid & 63;
  const int l15 = lane & 15, l4 = lane >> 4;
  const int wr = wave >> 1, wc = wave & 1;

  // staging: lane -> row = base + (lane>>2), phys slot = lane&3,
  // logical k-octet = (lane&3) ^ ((lane>>3)&3)   [g(row) = (row>>1)&3]
  const int srow = wave * 16 + (lane >> 2);
  const int sslot = ((lane & 3) ^ ((lane >> 3) & 3)) * 8;
  const u16* aS0 = A + (size_t)(m0 + srow) * 1024 + sslot;
  const u16* aS1 = A + (size_t)(m0 + 64 + srow) * 1024 + sslot;
  const u16* bS0 = W + (size_t)(n0 + srow) * 1024 + sslot;
  const u16* bS1 = W + (size_t)(n0 + 64 + srow) * 1024 + sslot;
  const int dOff0 = wave * 512, dOff1 = 2048 + wave * 512;

  // frag read offsets (elements), swizzled
  const int fswz = ((l15 >> 1) & 3);
  const int afBase = (wr * 64 + l15) * 32 + ((l4 ^ fswz) * 8);
  const int bfBase = (wc * 64 + l15) * 32 + ((l4 ^ fswz) * 8);

  f32x4 acc[4][4] = {};

  auto stage = [&](int buf, int kt) {
    const int ko = kt * 32;
    gld16(aS0 + ko, &As[buf][dOff0]);
    gld16(aS1 + ko, &As[buf][dOff1]);
    gld16(bS0 + ko, &Bs[buf][dOff0]);
    gld16(bS1 + ko, &Bs[buf][dOff1]);
  };

  stage(0, 0);
  stage(1, 1);

  int cb = 0;
  for (int kt = 0; kt < 32; ++kt) {
    if (kt < 31) asm volatile("s_waitcnt vmcnt(4)");  // buffer kt landed; kt+1 in flight
    else         asm volatile("s_waitcnt vmcnt(0)");
    __syncthreads();
    s16x8 af[4], bf[4];
    #pragma unroll
    for (int m = 0; m < 4; ++m) af[m] = *(const s16x8*)&As[cb][afBase + m * 512];
    #pragma unroll
    for (int n = 0; n < 4; ++n) bf[n] = *(const s16x8*)&Bs[cb][bfBase + n * 512];
    if (kt < 30) {
      int sb = cb + 2; if (sb >= 3) sb -= 3;
      stage(sb, kt + 2);
    }
    #pragma unroll
    for (int m = 0; m < 4; ++m)
      #pragma unroll
      for (int n = 0; n < 4; ++n)
        acc[m][n] = __builtin_amdgcn_mfma_f32_16x16x32_bf16(af[m], bf[n], acc[m][n], 0, 0, 0);
    cb = (cb + 1 == 3) ? 0 : cb + 1;
  }

  #pragma unroll
  for (int n = 0; n < 4; ++n) {
    const int col = n0 + wc * 64 + n * 16 + l15;
    #pragma unroll
    for (int m = 0; m < 4; ++m) {
      #pragma unroll
      for (int r = 0; r < 4; ++r) {
        const int row = m0 + wr * 64 + m * 16 + l4 * 4 + r;
        if constexpr (EPI == 0) {
          const float val = (acc[m][n][r] + (bias ? bias[col] : 0.f)) * alpha;
          const int bb = row >> 11, ss = row & 2047, hh = col >> 6, dd = col & 63;
          ((u16*)outp)[(((size_t)(bb * 16 + hh)) * 2048 + ss) * 64 + dd] = f2bf(val);
        } else if constexpr (EPI == 1) {
          ((float*)outp)[(size_t)row * 1024 + col] = acc[m][n][r] + (bias ? bias[col] : 0.f);
        } else {  // EPI==2: V^T out [B*NH][64][2048]
          const float val = acc[m][n][r] + bias[row];
          const int hh = row >> 6, dd = row & 63, bb = col >> 11, ss = col & 2047;
          ((u16*)outp)[(((size_t)(bb * 16 + hh)) * 64 + dd) * 2048 + ss] = f2bf(val);
        }
      }
    }
  }
}

__global__ __launch_bounds__(256) void gemm_qkv(
    const u16* __restrict__ qbf, const u16* __restrict__ kvbf,
    const u16* __restrict__ wqb, const u16* __restrict__ wkb, const u16* __restrict__ wvb,
    const float* __restrict__ bq, const float* __restrict__ bv,
    u16* __restrict__ Qh, u16* __restrict__ Kh, u16* __restrict__ Vt)
{
  const int bid = blockIdx.x;
  const int swz = (bid & 7) * 32 + (bid >> 3);   // XCD-contiguous chunks
  const int which = blockIdx.y;
  if (which == 0)
    gemm_body<0>(qbf, wqb, bq, Qh, 0.125f, (swz >> 3) * 128, (swz & 7) * 128);
  else if (which == 1)
    gemm_body<0>(kvbf, wkb, nullptr, Kh, 1.0f, (swz >> 3) * 128, (swz & 7) * 128);
  else   // V^T = Wv * KV^T  (M=1024 d-rows, N=4096 s-cols)
    gemm_body<2>(wvb, kvbf, bv, Vt, 1.0f, (swz >> 5) * 128, (swz & 31) * 128);
}

__global__ __launch_bounds__(256) void gemm_out(
    const u16* __restrict__ ctx, const u16* __restrict__ wob,
    const float* __restrict__ bo, float* __restrict__ out)
{
  const int bid = blockIdx.x;
  const int swz = (bid & 7) * 32 + (bid >> 3);
  gemm_body<1>(ctx, wob, bo, out, 1.0f, (swz >> 3) * 128, (swz & 7) * 128);
}

// ---------------- flash attention: 128 q-rows/block, 32 q/wave ----------------
// grid 512 blocks (XCD-chunked: 4 heads per XCD -> K/V L2-resident).
// S^T = K*Q^T (kv lane-local). Per wave 2 q-groups g: 2x MFMA per frag read.
// LDS rows are 128B; XOR swizzle phys_slot = slot ^ (row&7); staging gld16
// covers 8 rows x 128B with pre-swizzled global source.
__global__ __launch_bounds__(256) void attn_kernel(
    const u16* __restrict__ Qh, const u16* __restrict__ Kh,
    const u16* __restrict__ Vt, const u16* __restrict__ am,
    u16* __restrict__ ctx)
{
  __shared__ u16 Ks[2][4096];        // [64 kv][64 d]
  __shared__ u16 Vs[2][4096];        // [64 d][64 kv]
  __shared__ u16 Pl[4][2][1024];     // per wave per g: [16 q][64 kv]
  const int tid = threadIdx.x, wave = tid >> 6, lane = tid & 63;
  const int l15 = lane & 15, l4 = lane >> 4;
  const int x7 = l15 & 7;
  const int bid = blockIdx.x;
  const int pos = (bid & 7) * 64 + (bid >> 3);   // XCD-chunked (512 = 8*64)
  const int hh = pos >> 4, qt = pos & 15;
  const int b = hh >> 4, h = hh & 15;
  const int q0 = qt * 128;
  const u16* Qb = Qh + (size_t)hh * 2048 * 64;
  const u16* Kb = Kh + (size_t)hh * 2048 * 64;
  const u16* Vb = Vt + (size_t)hh * 64 * 2048;

  // Q B-frags (col=q=l15, k=d=l4*8+j), scale folded at projection
  s16x8 qf[2][2];
  const u16* amrow[2];
  #pragma unroll
  for (int g = 0; g < 2; ++g) {
    const int qrow = q0 + wave * 32 + g * 16 + l15;
    qf[g][0] = *(const s16x8*)(Qb + (size_t)qrow * 64 + l4 * 8);
    qf[g][1] = *(const s16x8*)(Qb + (size_t)qrow * 64 + 32 + l4 * 8);
    amrow[g] = am + ((size_t)b * 2048 + qrow) * 2048;
  }

  // staging: lane -> row = wave*16 + (lane>>3) (+8), phys slot = lane&7,
  // logical slot = (lane&7) ^ ((lane>>3)&7)
  const int sr = wave * 16 + (lane >> 3);
  const int ss = ((lane & 7) ^ ((lane >> 3) & 7)) * 8;
  const u16* kS0 = Kb + (size_t)sr * 64 + ss;
  const u16* kS1 = Kb + (size_t)(sr + 8) * 64 + ss;
  const u16* vS0 = Vb + (size_t)sr * 2048 + ss;
  const u16* vS1 = Vb + (size_t)(sr + 8) * 2048 + ss;
  const int kd0 = wave * 1024, kd1 = kd0 + 512;

  auto stage = [&](int buf, int kt) {
    const int kv0 = kt * 64;
    gld16(kS0 + (size_t)kv0 * 64, &Ks[buf][kd0]);
    gld16(kS1 + (size_t)kv0 * 64, &Ks[buf][kd1]);
    gld16(vS0 + kv0, &Vs[buf][kd0]);
    gld16(vS1 + kv0, &Vs[buf][kd1]);
  };

  f32x4 of[2][4] = {};
  float m_run[2] = {-1e30f, -1e30f}, l_run[2] = {0.f, 0.f};

  stage(0, 0);
  asm volatile("s_waitcnt vmcnt(0)");
  __syncthreads();

  int cur = 0;
  for (int kt = 0; kt < 32; ++kt) {
    if (kt < 31) stage(cur ^ 1, kt + 1);
    const int kv0 = kt * 64;

    // mask loads (kv contiguous per lane)
    ushort4 mk[2][4];
    #pragma unroll
    for (int g = 0; g < 2; ++g)
      #pragma unroll
      for (int nf = 0; nf < 4; ++nf)
        mk[g][nf] = *(const ushort4*)(amrow[g] + kv0 + nf * 16 + l4 * 4);

    // S^T = K * Q^T : lane holds q=l15, kv_local = nf*16 + l4*4 + r
    f32x4 sf[2][4];
    __builtin_amdgcn_s_setprio(1);
    #pragma unroll
    for (int nf = 0; nf < 4; ++nf) {
      const s16x8 ka0 = *(const s16x8*)&Ks[cur][nf * 1024 + l15 * 64 + ((l4 ^ x7) * 8)];
      const s16x8 ka1 = *(const s16x8*)&Ks[cur][nf * 1024 + l15 * 64 + (((4 + l4) ^ x7) * 8)];
      #pragma unroll
      for (int g = 0; g < 2; ++g) {
        f32x4 s = {0.f, 0.f, 0.f, 0.f};
        s = __builtin_amdgcn_mfma_f32_16x16x32_bf16(ka0, qf[g][0], s, 0, 0, 0);
        s = __builtin_amdgcn_mfma_f32_16x16x32_bf16(ka1, qf[g][1], s, 0, 0, 0);
        sf[g][nf] = s;
      }
    }
    __builtin_amdgcn_s_setprio(0);

    // online softmax per q-group
    #pragma unroll
    for (int g = 0; g < 2; ++g) {
      float tmax = -1e30f;
      #pragma unroll
      for (int nf = 0; nf < 4; ++nf)
        #pragma unroll
        for (int r = 0; r < 4; ++r) {
          const float sv = sf[g][nf][r] + bf2f(((const u16*)&mk[g][nf])[r]);
          sf[g][nf][r] = sv;
          tmax = fmaxf(tmax, sv);
        }
      tmax = fmaxf(tmax, __shfl_xor(tmax, 16));
      tmax = fmaxf(tmax, __shfl_xor(tmax, 32));

      const float mn = fmaxf(m_run[g], tmax);
      const float sc = __expf(m_run[g] - mn);
      m_run[g] = mn;
      float psum = 0.f;
      u32* pw = (u32*)&Pl[wave][g][0];
      #pragma unroll
      for (int nf = 0; nf < 4; ++nf) {
        const float p0 = __expf(sf[g][nf][0] - mn), p1 = __expf(sf[g][nf][1] - mn);
        const float p2 = __expf(sf[g][nf][2] - mn), p3 = __expf(sf[g][nf][3] - mn);
        psum += (p0 + p1) + (p2 + p3);
        // logical 8B chunk: slot = nf*2+(l4>>1), half = l4&1; phys slot ^= x7
        u32* w = pw + l15 * 32 + (((nf * 2 + (l4 >> 1)) ^ x7) * 4) + (l4 & 1) * 2;
        w[0] = pack2(p0, p1);
        w[1] = pack2(p2, p3);
      }
      psum += __shfl_xor(psum, 16);
      psum += __shfl_xor(psum, 32);
      l_run[g] = l_run[g] * sc + psum;

      float sq[4];
      #pragma unroll
      for (int r = 0; r < 4; ++r) sq[r] = __shfl(sc, l4 * 4 + r);
      #pragma unroll
      for (int nd = 0; nd < 4; ++nd)
        #pragma unroll
        for (int r = 0; r < 4; ++r) of[g][nd][r] *= sq[r];
    }

    // O += P * V
    __builtin_amdgcn_s_setprio(1);
    #pragma unroll
    for (int kh = 0; kh < 2; ++kh) {
      s16x8 pa[2];
      #pragma unroll
      for (int g = 0; g < 2; ++g)
        pa[g] = *(const s16x8*)&Pl[wave][g][l15 * 64 + (((kh * 4 + l4) ^ x7) * 8)];
      #pragma unroll
      for (int nd = 0; nd < 4; ++nd) {
        const s16x8 vb = *(const s16x8*)&Vs[cur][nd * 1024 + l15 * 64 + (((kh * 4 + l4) ^ x7) * 8)];
        #pragma unroll
        for (int g = 0; g < 2; ++g)
          of[g][nd] = __builtin_amdgcn_mfma_f32_16x16x32_bf16(pa[g], vb, of[g][nd], 0, 0, 0);
      }
    }
    __builtin_amdgcn_s_setprio(0);

    asm volatile("s_waitcnt vmcnt(0)");
    __syncthreads();
    cur ^= 1;
  }

  // epilogue: normalize + write ctx [B][S][H] bf16
  #pragma unroll
  for (int g = 0; g < 2; ++g) {
    const float inv = 1.f / l_run[g];
    float invq[4];
    #pragma unroll
    for (int r = 0; r < 4; ++r) invq[r] = __shfl(inv, l4 * 4 + r);
    #pragma unroll
    for (int r = 0; r < 4; ++r) {
      const int qg = q0 + wave * 32 + g * 16 + l4 * 4 + r;
      const size_t rowbase = ((size_t)b * 2048 + qg) * 1024 + h * 64;
      #pragma unroll
      for (int nd = 0; nd < 4; ++nd)
        ctx[rowbase + nd * 16 + l15] = f2bf(of[g][nd][r] * invq[r]);
    }
  }
}

// ---------------- launcher ----------------
extern "C" void kernel_launch(void* const* d_in, const int* in_sizes, int n_in,
                              void* d_out, int out_size, void* d_ws, size_t ws_size,
                              hipStream_t stream)
{
  const float* qs = (const float*)d_in[0];
  const float* kvs = (const float*)d_in[1];
  const float* mk = (const float*)d_in[2];
  const float* Wq = (const float*)d_in[3];
  const float* bq = (const float*)d_in[4];
  const float* Wk = (const float*)d_in[5];
  const float* Wv = (const float*)d_in[6];
  const float* bv = (const float*)d_in[7];
  const float* Wo = (const float*)d_in[8];
  const float* bo = (const float*)d_in[9];
  float* out = (float*)d_out;

  char* ws = (char*)d_ws;
  u16* q_bf  = (u16*)(ws + 0);
  u16* kv_bf = (u16*)(ws + 8388608);
  u16* wq_bf = (u16*)(ws + 16777216);
  u16* wk_bf = (u16*)(ws + 18874368);
  u16* wv_bf = (u16*)(ws + 20971520);
  u16* wo_bf = (u16*)(ws + 23068672);
  u16* am_bf = (u16*)(ws + 25165824);
  u16* Qhp   = (u16*)(ws + 41943040);   // [B*NH][2048][64]
  u16* Khp   = (u16*)(ws + 50331648);   // [B*NH][2048][64]
  u16* Vtp   = (u16*)(ws + 58720256);   // [B*NH][64][2048]  (pre-transposed)
  u16* ctxp  = (u16*)(ws + 67108864);   // [B][2048][1024]

  prep_kernel<<<dim3(2048), dim3(256), 0, stream>>>(
      qs, kvs, mk, Wq, Wk, Wv, Wo, q_bf, kv_bf, am_bf, wq_bf, wk_bf, wv_bf, wo_bf);

  gemm_qkv<<<dim3(256, 3), dim3(256), 0, stream>>>(
      q_bf, kv_bf, wq_bf, wk_bf, wv_bf, bq, bv, Qhp, Khp, Vtp);

  attn_kernel<<<dim3(512), dim3(256), 0, stream>>>(Qhp, Khp, Vtp, am_bf, ctxp);

  gemm_out<<<dim3(256), dim3(256), 0, stream>>>(ctxp, wo_bf, bo, out);
}